// Round 9
// baseline (450.199 us; speedup 1.0000x reference)
//
#include <hip/hip_runtime.h>
#include <hip/hip_bf16.h>
#include <hip/hip_fp16.h>
#include <math.h>

#define EPB 8192   // edges per partition block
#define BPB 256    // nodes per bucket

typedef _Float16 v8h __attribute__((ext_vector_type(8)));
typedef float v4f __attribute__((ext_vector_type(4)));

// ---------------- wave helpers (wave = 64 on gfx950) ----------------
__device__ inline float sum16(float v) {  // reduce within 16-lane groups
#pragma unroll
  for (int off = 1; off < 16; off <<= 1) v += __shfl_xor(v, off);
  return v;
}

// load 8 consecutive fp32 as 8 halves (16B)
__device__ inline uint4 load8h(const float* p) {
  float4 a = *(const float4*)p;
  float4 b = *(const float4*)(p + 4);
  union { __half2 h[4]; uint4 u; } pk;
  pk.h[0] = __floats2half2_rn(a.x, a.y);
  pk.h[1] = __floats2half2_rn(a.z, a.w);
  pk.h[2] = __floats2half2_rn(b.x, b.y);
  pk.h[3] = __floats2half2_rn(b.z, b.w);
  return pk.u;
}

// ---------------- bucket partition (CSR build) ----------------
__global__ __launch_bounds__(256) void k_pcount(const int* __restrict__ ei,
                                                int* __restrict__ btot,
                                                int* __restrict__ blkoff,
                                                int nE, int n, int PB, int NB) {
  __shared__ int hist[512];
  int p = blockIdx.x, t = threadIdx.x;
  for (int i = t; i < NB; i += 256) hist[i] = 0;
  __syncthreads();
  int e0 = p * EPB;
  int e1 = min(e0 + EPB, nE);
  for (int i = e0 + t; i < e1; i += 256) {
    int d = ei[nE + i];
    if ((unsigned)d < (unsigned)n) atomicAdd(&hist[d >> 8], 1);
  }
  __syncthreads();
  for (int i = t; i < NB; i += 256) {
    int h = hist[i];
    int off = atomicAdd(&btot[i], h);
    blkoff[i * PB + p] = off;
  }
}

__global__ __launch_bounds__(256) void k_bscan(const int* __restrict__ btot,
                                               int* __restrict__ bbase, int NB) {
  __shared__ int s[256];
  int t = threadIdx.x;
  int v0 = (2 * t < NB) ? btot[2 * t] : 0;
  int v1 = (2 * t + 1 < NB) ? btot[2 * t + 1] : 0;
  int sum = v0 + v1;
  s[t] = sum;
  __syncthreads();
  for (int off = 1; off < 256; off <<= 1) {
    int x = (t >= off) ? s[t - off] : 0;
    __syncthreads();
    s[t] += x;
    __syncthreads();
  }
  int excl = s[t] - sum;
  if (2 * t < NB) bbase[2 * t] = excl;
  if (2 * t + 1 < NB) bbase[2 * t + 1] = excl + v0;
  if (t == 0) bbase[NB] = s[255];
}

__global__ __launch_bounds__(256) void k_ppart(const int* __restrict__ ei,
                                               const int* __restrict__ bbase,
                                               const int* __restrict__ blkoff,
                                               int2* __restrict__ part,
                                               int nE, int n, int PB, int NB) {
  __shared__ int cur[512];
  int p = blockIdx.x, t = threadIdx.x;
  for (int i = t; i < NB; i += 256) cur[i] = bbase[i] + blkoff[i * PB + p];
  __syncthreads();
  int e0 = p * EPB;
  int e1 = min(e0 + EPB, nE);
  for (int i = e0 + t; i < e1; i += 256) {
    int d = ei[nE + i];
    int s = ei[i];
    if ((unsigned)d < (unsigned)n) {
      int pos = atomicAdd(&cur[d >> 8], 1);
      part[pos] = make_int2(s, d);
    }
  }
}

__global__ __launch_bounds__(256) void k_bucket(const int2* __restrict__ part,
                                                const int* __restrict__ bbase,
                                                int* __restrict__ rowptr,
                                                int* __restrict__ col,
                                                int NB, int n) {
  __shared__ int sdeg[256];
  __shared__ int sscan[256];
  __shared__ int lcol[8448];
  int b = blockIdx.x, t = threadIdx.x;
  int node0 = b * BPB;
  int ebeg = bbase[b];
  int eend = bbase[b + 1];
  int cnt = eend - ebeg;
  if (cnt > 8192) cnt = 8192;
  int nloc = n - node0;
  if (nloc > BPB) nloc = BPB;

  sdeg[t] = (t < nloc) ? 1 : 0;
  __syncthreads();
  for (int i = t; i < cnt; i += 256) {
    int d = part[ebeg + i].y;
    atomicAdd(&sdeg[d - node0], 1);
  }
  __syncthreads();
  int v = sdeg[t];
  sscan[t] = v;
  __syncthreads();
  for (int off = 1; off < 256; off <<= 1) {
    int x = (t >= off) ? sscan[t - off] : 0;
    __syncthreads();
    sscan[t] += x;
    __syncthreads();
  }
  int excl = sscan[t] - v;
  int gbase = ebeg + node0;
  if (t < nloc) rowptr[node0 + t] = gbase + excl;
  if (b == NB - 1 && t == 0) rowptr[n] = bbase[NB] + n;
  if (t < nloc) lcol[excl] = node0 + t;
  sdeg[t] = excl + 1;
  __syncthreads();
  for (int i = t; i < cnt; i += 256) {
    int2 e = part[ebeg + i];
    int pos = atomicAdd(&sdeg[e.y - node0], 1);
    lcol[pos] = e.x;
  }
  __syncthreads();
  int T = cnt + nloc;
  for (int i = t; i < T; i += 256) col[gbase + i] = lcol[i];
}

// ---------------- MFMA GEMM + fused alpha; SLICE-MAJOR fp16 output ----------------
// H stored as Hs[slice][node][16ch] (slice = c>>4, 32B per node per slice):
// keeps each XCD's gather working set line-pure (agg slice kernel).
// SLICED_IN: X is slice-major fp16 (layer-2 input), else row-major fp32.
template <typename T, bool SLICED_IN>
__global__ __launch_bounds__(256) void k_linear_mfma(const T* __restrict__ X,
                                                     const float* __restrict__ W,
                                                     const float* __restrict__ a_src,
                                                     const float* __restrict__ a_dst,
                                                     __half* __restrict__ H16,
                                                     float* __restrict__ as_,
                                                     float* __restrict__ ad_, int nrows) {
  __shared__ uint4 Xs[64 * 16];   // 16 KB
  __shared__ uint4 Ws[128 * 16];  // 32 KB
  int t = threadIdx.x;
  int row0 = blockIdx.x * 64;

  // stage X tile: 1024 16B chunks; chunk j of row r covers k = j*8..j*8+7
#pragma unroll
  for (int i = 0; i < 4; ++i) {
    int idx = t + i * 256;
    int r = idx >> 4;
    int j = idx & 15;
    uint4 u = make_uint4(0u, 0u, 0u, 0u);
    int rr = row0 + r;
    if (rr < nrows) {
      if (SLICED_IN) {
        const __half* Xh = (const __half*)X;
        u = *(const uint4*)&Xh[((size_t)(j >> 1) * nrows + rr) * 16 + (j & 1) * 8];
      } else {
        u = load8h((const float*)X + (size_t)rr * 128 + j * 8);
      }
    }
    Xs[r * 16 + (j ^ (r & 15))] = u;
  }
  // stage W: 2048 chunks (fp32 source, [c][k])
#pragma unroll
  for (int i = 0; i < 8; ++i) {
    int idx = t + i * 256;
    int c = idx >> 4;
    int j = idx & 15;
    Ws[c * 16 + (j ^ (c & 15))] = load8h(&W[(size_t)c * 128 + j * 8]);
  }
  __syncthreads();

  int w = t >> 6;  // wave -> rows w*16..+15
  int lane = t & 63;
  int li = lane & 15;
  int quad = lane >> 4;

  v4f acc[8];
#pragma unroll
  for (int ct = 0; ct < 8; ++ct) acc[ct] = (v4f){0.f, 0.f, 0.f, 0.f};

#pragma unroll
  for (int kk = 0; kk < 4; ++kk) {
    int ch = kk * 4 + quad;
    union { uint4 u; v8h h; } av;
    av.u = Xs[(w * 16 + li) * 16 + (ch ^ li)];
#pragma unroll
    for (int ct = 0; ct < 8; ++ct) {
      union { uint4 u; v8h h; } bv;
      bv.u = Ws[(ct * 16 + li) * 16 + (ch ^ li)];
      acc[ct] = __builtin_amdgcn_mfma_f32_16x16x32_f16(av.h, bv.h, acc[ct], 0, 0, 0);
    }
  }

  // fused alpha (C/D layout: col=lane&15, row=quad*4+reg)
  float asum[4] = {0.f, 0.f, 0.f, 0.f};
  float adsum[4] = {0.f, 0.f, 0.f, 0.f};
#pragma unroll
  for (int ct = 0; ct < 8; ++ct) {
    float sa = a_src[ct * 16 + li];
    float da = a_dst[ct * 16 + li];
#pragma unroll
    for (int reg = 0; reg < 4; ++reg) {
      asum[reg] = fmaf(acc[ct][reg], sa, asum[reg]);
      adsum[reg] = fmaf(acc[ct][reg], da, adsum[reg]);
    }
  }
#pragma unroll
  for (int reg = 0; reg < 4; ++reg) {
    asum[reg] = sum16(asum[reg]);
    adsum[reg] = sum16(adsum[reg]);
  }
  if (li == 0) {
#pragma unroll
    for (int reg = 0; reg < 4; ++reg) {
      int r = row0 + w * 16 + quad * 4 + reg;
      if (r < nrows) {
        as_[r] = asum[reg];
        ad_[r] = adsum[reg];
      }
    }
  }

  // slice-major store: channel c = ct*16+li -> slice ct, offset r*16+li
#pragma unroll
  for (int ct = 0; ct < 8; ++ct) {
#pragma unroll
    for (int reg = 0; reg < 4; ++reg) {
      float v0 = acc[ct][reg];
      float v1 = __shfl_xor(v0, 1);
      if (!(li & 1)) {
        int r = row0 + w * 16 + quad * 4 + reg;
        if (r < nrows) {
          __half2 hh = __floats2half2_rn(v0, v1);
          *(__half2*)&H16[((size_t)ct * nrows + r) * 16 + li] = hh;
        }
      }
    }
  }
}

// ---------------- edge weights: wexp[e], 1/den[node] (no-max softmax) ----------------
__global__ __launch_bounds__(256) void k_edgew(const float* __restrict__ as_,
                                               const float* __restrict__ ad_,
                                               const int* __restrict__ rowptr,
                                               const int* __restrict__ col,
                                               float* __restrict__ wexp,
                                               float* __restrict__ deninv, int n) {
  int gid = blockIdx.x * 256 + threadIdx.x;
  int wid = gid >> 6;
  int lane = gid & 63;
  int g = lane >> 4;
  int li = lane & 15;
  int node = wid * 4 + g;
  bool valid = node < n;
  int beg = 0, end = 0;
  float adv = 0.f;
  if (valid) {
    beg = rowptr[node];
    end = rowptr[node + 1];
    adv = ad_[node];
  }
  int deg = end - beg;
  float den_l = 0.f;
  for (int j = li; j < deg; j += 16) {
    int s = col[beg + j];
    if ((unsigned)s >= (unsigned)n) s = 0;
    float v = as_[s] + adv;
    v = (v > 0.f) ? v : 0.2f * v;
    float wv = __expf(v);
    wexp[beg + j] = wv;
    den_l += wv;
  }
  float den = sum16(den_l);
  if (li == 0 && valid) deninv[node] = 1.0f / den;
}

// ---------------- sliced GAT aggregation ----------------
// slice = blockIdx.x & 7 (round-robin -> XCD affinity heuristic, perf-only):
// per-XCD gather working set = N*32B = 3.2MB -> L2-resident. Wave = 4 nodes
// x 16 lanes; lane pair (p=li&1) owns 16B of edge q=li>>1; 8 edges/trip.
__global__ __launch_bounds__(256) void k_agg_slice(const __half* __restrict__ Hs,
                                                   const float* __restrict__ wexp,
                                                   const float* __restrict__ deninv,
                                                   const int* __restrict__ rowptr,
                                                   const int* __restrict__ col,
                                                   const float* __restrict__ bias,
                                                   __half* __restrict__ Os, int n) {
  int slice = blockIdx.x & 7;
  int nb = blockIdx.x >> 3;
  int w = threadIdx.x >> 6;
  int lane = threadIdx.x & 63;
  int g = lane >> 4;
  int li = lane & 15;
  int p = li & 1;
  int q = li >> 1;
  int node = nb * 16 + w * 4 + g;
  bool valid = node < n;
  int beg = 0, end = 0;
  if (valid) {
    beg = rowptr[node];
    end = rowptr[node + 1];
  }
  int deg = end - beg;
  const __half* hsl = Hs + (size_t)slice * n * 16;

  float acc[8];
#pragma unroll
  for (int k = 0; k < 8; ++k) acc[k] = 0.f;

  for (int base = 0; base < deg; base += 8) {
    int j = base + q;
    int s = 0;
    float wgt = 0.f;
    if (j < deg) {
      s = col[beg + j];
      if ((unsigned)s >= (unsigned)n) s = 0;
      wgt = wexp[beg + j];
    }
    uint4 hv = *(const uint4*)(hsl + (size_t)s * 16 + p * 8);
    float2 f0 = __half22float2(*(__half2*)&hv.x);
    float2 f1 = __half22float2(*(__half2*)&hv.y);
    float2 f2 = __half22float2(*(__half2*)&hv.z);
    float2 f3 = __half22float2(*(__half2*)&hv.w);
    acc[0] = fmaf(f0.x, wgt, acc[0]);
    acc[1] = fmaf(f0.y, wgt, acc[1]);
    acc[2] = fmaf(f1.x, wgt, acc[2]);
    acc[3] = fmaf(f1.y, wgt, acc[3]);
    acc[4] = fmaf(f2.x, wgt, acc[4]);
    acc[5] = fmaf(f2.y, wgt, acc[5]);
    acc[6] = fmaf(f3.x, wgt, acc[6]);
    acc[7] = fmaf(f3.y, wgt, acc[7]);
  }

  // reduce over the 8 edge-pairs (same parity p): butterfly xor 2,4,8
#pragma unroll
  for (int off = 2; off <= 8; off <<= 1) {
#pragma unroll
    for (int k = 0; k < 8; ++k) acc[k] += __shfl_xor(acc[k], off);
  }

  float inv = valid ? deninv[node] : 0.f;
  int c0 = slice * 16 + p * 8;
  float4 b0 = *(const float4*)&bias[c0];
  float4 b1 = *(const float4*)&bias[c0 + 4];
  float o0 = fmaxf(fmaf(acc[0], inv, b0.x), 0.f);
  float o1 = fmaxf(fmaf(acc[1], inv, b0.y), 0.f);
  float o2 = fmaxf(fmaf(acc[2], inv, b0.z), 0.f);
  float o3 = fmaxf(fmaf(acc[3], inv, b0.w), 0.f);
  float o4 = fmaxf(fmaf(acc[4], inv, b1.x), 0.f);
  float o5 = fmaxf(fmaf(acc[5], inv, b1.y), 0.f);
  float o6 = fmaxf(fmaf(acc[6], inv, b1.z), 0.f);
  float o7 = fmaxf(fmaf(acc[7], inv, b1.w), 0.f);

  if (li < 2 && valid) {
    union { __half2 h2[4]; uint4 u; } pk;
    pk.h2[0] = __floats2half2_rn(o0, o1);
    pk.h2[1] = __floats2half2_rn(o2, o3);
    pk.h2[2] = __floats2half2_rn(o4, o5);
    pk.h2[3] = __floats2half2_rn(o6, o7);
    *(uint4*)&Os[((size_t)slice * n + node) * 16 + p * 8] = pk.u;
  }
}

// ---------------- classifier heads (reads slice-major fp16 features) ----------------
__global__ __launch_bounds__(256) void k_heads(const __half* __restrict__ Fs,
                                               const float* __restrict__ Wf,
                                               const float* __restrict__ bf,
                                               const float* __restrict__ Wsk,
                                               const float* __restrict__ bs,
                                               float* __restrict__ out, int n) {
  int gid = blockIdx.x * 256 + threadIdx.x;
  int wid = gid >> 6;
  int lane = gid & 63;
  int g = lane >> 4;
  int li = lane & 15;
  int node = wid * 4 + g;
  if (node >= n) return;
  // lane li owns channels li*8..+7 -> slice li>>1, half (li&1)*8
  uint4 hv = *(const uint4*)&Fs[((size_t)(li >> 1) * n + node) * 16 + (li & 1) * 8];
  float2 f0 = __half22float2(*(__half2*)&hv.x);
  float2 f1 = __half22float2(*(__half2*)&hv.y);
  float2 f2 = __half22float2(*(__half2*)&hv.z);
  float2 f3 = __half22float2(*(__half2*)&hv.w);
  float p[10];
#pragma unroll
  for (int j = 0; j < 3; ++j) {
    float4 w0 = *(const float4*)&Wf[(size_t)j * 128 + li * 8];
    float4 w1 = *(const float4*)&Wf[(size_t)j * 128 + li * 8 + 4];
    p[j] = f0.x * w0.x + f0.y * w0.y + f1.x * w0.z + f1.y * w0.w +
           f2.x * w1.x + f2.y * w1.y + f3.x * w1.z + f3.y * w1.w;
  }
#pragma unroll
  for (int j = 0; j < 7; ++j) {
    float4 w0 = *(const float4*)&Wsk[(size_t)j * 128 + li * 8];
    float4 w1 = *(const float4*)&Wsk[(size_t)j * 128 + li * 8 + 4];
    p[3 + j] = f0.x * w0.x + f0.y * w0.y + f1.x * w0.z + f1.y * w0.w +
               f2.x * w1.x + f2.y * w1.y + f3.x * w1.z + f3.y * w1.w;
  }
#pragma unroll
  for (int j = 0; j < 10; ++j) p[j] = sum16(p[j]);
  if (li == 0) {
#pragma unroll
    for (int j = 0; j < 3; ++j) out[(size_t)node * 3 + j] = p[j] + bf[j];
    float* sk = out + (size_t)n * 3;
#pragma unroll
    for (int j = 0; j < 7; ++j) sk[(size_t)node * 7 + j] = p[3 + j] + bs[j];
  }
}

// ---------------- launch ----------------
extern "C" void kernel_launch(void* const* d_in, const int* in_sizes, int n_in,
                              void* d_out, int out_size, void* d_ws, size_t ws_size,
                              hipStream_t stream) {
  const float* x = (const float*)d_in[0];
  const int* ei = (const int*)d_in[1];  // [2, E] int32
  const float* W1 = (const float*)d_in[2];
  const float* a_src1 = (const float*)d_in[3];
  const float* a_dst1 = (const float*)d_in[4];
  const float* b1 = (const float*)d_in[5];
  const float* W2 = (const float*)d_in[6];
  const float* a_src2 = (const float*)d_in[7];
  const float* a_dst2 = (const float*)d_in[8];
  const float* b2 = (const float*)d_in[9];
  const float* Wf = (const float*)d_in[10];
  const float* bf = (const float*)d_in[11];
  const float* Wsk = (const float*)d_in[12];
  const float* bs = (const float*)d_in[13];
  float* out = (float*)d_out;

  const int N = in_sizes[0] / 128;
  const int nE = in_sizes[1] / 2;
  const int NB = (N + BPB - 1) / BPB;
  const int PB = (nE + EPB - 1) / EPB;
  const int NCNT = NB * PB;

  char* w = (char*)d_ws;
  auto carve = [&](size_t bytes) {
    char* p = w;
    w += (bytes + 255) & ~(size_t)255;
    return (void*)p;
  };
  __half* H16 = (__half*)carve((size_t)N * 128 * 2);  // GEMM out, slice-major
  __half* B16 = (__half*)carve((size_t)N * 128 * 2);  // agg out, slice-major
  float* as_ = (float*)carve((size_t)N * 4);
  float* ad_ = (float*)carve((size_t)N * 4);
  float* deninv = (float*)carve((size_t)N * 4);
  float* wexp = (float*)carve((size_t)(nE + N) * 4);
  int* rowptr = (int*)carve((size_t)(N + 1) * 4);
  int* col = (int*)carve((size_t)(nE + N) * 4);
  int* btot = (int*)carve((size_t)(NB + 1) * 4);
  int* bbase = (int*)carve((size_t)(NB + 1) * 4);
  int* blkoff = (int*)carve((size_t)NCNT * 4);
  int2* part = (int2*)carve((size_t)nE * 8);

  dim3 b256(256);

  // ---- CSR build ----
  hipMemsetAsync(btot, 0, (size_t)(NB + 1) * 4, stream);
  k_pcount<<<PB, b256, 0, stream>>>(ei, btot, blkoff, nE, N, PB, NB);
  k_bscan<<<1, b256, 0, stream>>>(btot, bbase, NB);
  k_ppart<<<PB, b256, 0, stream>>>(ei, bbase, blkoff, part, nE, N, PB, NB);
  k_bucket<<<NB, b256, 0, stream>>>(part, bbase, rowptr, col, NB, N);

  const int gemm_blocks = (N + 63) / 64;
  const int nodewave_blocks = (((N + 3) / 4) * 64 + 255) / 256;  // 4 nodes/wave
  const int agg_blocks = ((N + 15) / 16) * 8;                    // x8 slices

  // ---- layer 1 ----
  k_linear_mfma<float, false><<<gemm_blocks, b256, 0, stream>>>(x, W1, a_src1, a_dst1,
                                                                H16, as_, ad_, N);
  k_edgew<<<nodewave_blocks, b256, 0, stream>>>(as_, ad_, rowptr, col, wexp, deninv, N);
  k_agg_slice<<<agg_blocks, b256, 0, stream>>>(H16, wexp, deninv, rowptr, col, b1, B16, N);

  // ---- layer 2 ----
  k_linear_mfma<__half, true><<<gemm_blocks, b256, 0, stream>>>((const __half*)B16, W2,
                                                                a_src2, a_dst2, H16, as_, ad_, N);
  k_edgew<<<nodewave_blocks, b256, 0, stream>>>(as_, ad_, rowptr, col, wexp, deninv, N);
  k_agg_slice<<<agg_blocks, b256, 0, stream>>>(H16, wexp, deninv, rowptr, col, b2, B16, N);

  // ---- heads ----
  k_heads<<<nodewave_blocks, b256, 0, stream>>>(B16, Wf, bf, Wsk, bs, out, N);
}

// Round 10
// 350.017 us; speedup vs baseline: 1.2862x; 1.2862x over previous
//
#include <hip/hip_runtime.h>
#include <hip/hip_bf16.h>
#include <hip/hip_fp16.h>
#include <math.h>

#define EPB 8192   // edges per partition block
#define BPB 256    // nodes per bucket
#define DBLK 1024  // nodes per degree-sort block

typedef _Float16 v8h __attribute__((ext_vector_type(8)));
typedef float v4f __attribute__((ext_vector_type(4)));

// ---------------- wave helpers (wave = 64 on gfx950) ----------------
__device__ inline float sum16(float v) {  // reduce within 16-lane groups
#pragma unroll
  for (int off = 1; off < 16; off <<= 1) v += __shfl_xor(v, off);
  return v;
}

// load 8 consecutive values as 8 halves (16B)
__device__ inline uint4 load8h(const float* p) {
  float4 a = *(const float4*)p;
  float4 b = *(const float4*)(p + 4);
  union { __half2 h[4]; uint4 u; } pk;
  pk.h[0] = __floats2half2_rn(a.x, a.y);
  pk.h[1] = __floats2half2_rn(a.z, a.w);
  pk.h[2] = __floats2half2_rn(b.x, b.y);
  pk.h[3] = __floats2half2_rn(b.z, b.w);
  return pk.u;
}
__device__ inline uint4 load8h(const __half* p) { return *(const uint4*)p; }

// ---------------- bucket partition (CSR build) ----------------
__global__ __launch_bounds__(256) void k_pcount(const int* __restrict__ ei,
                                                int* __restrict__ btot,
                                                int* __restrict__ blkoff,
                                                int nE, int n, int PB, int NB) {
  __shared__ int hist[512];
  int p = blockIdx.x, t = threadIdx.x;
  for (int i = t; i < NB; i += 256) hist[i] = 0;
  __syncthreads();
  int e0 = p * EPB;
  int e1 = min(e0 + EPB, nE);
  for (int i = e0 + t; i < e1; i += 256) {
    int d = ei[nE + i];
    if ((unsigned)d < (unsigned)n) atomicAdd(&hist[d >> 8], 1);
  }
  __syncthreads();
  for (int i = t; i < NB; i += 256) {
    int h = hist[i];
    int off = atomicAdd(&btot[i], h);
    blkoff[i * PB + p] = off;
  }
}

__global__ __launch_bounds__(256) void k_bscan(const int* __restrict__ btot,
                                               int* __restrict__ bbase, int NB) {
  __shared__ int s[256];
  int t = threadIdx.x;
  int v0 = (2 * t < NB) ? btot[2 * t] : 0;
  int v1 = (2 * t + 1 < NB) ? btot[2 * t + 1] : 0;
  int sum = v0 + v1;
  s[t] = sum;
  __syncthreads();
  for (int off = 1; off < 256; off <<= 1) {
    int x = (t >= off) ? s[t - off] : 0;
    __syncthreads();
    s[t] += x;
    __syncthreads();
  }
  int excl = s[t] - sum;
  if (2 * t < NB) bbase[2 * t] = excl;
  if (2 * t + 1 < NB) bbase[2 * t + 1] = excl + v0;
  if (t == 0) bbase[NB] = s[255];
}

// part entry packed: (src << 8) | (dst & 255)  [n < 2^24]
__global__ __launch_bounds__(256) void k_ppart(const int* __restrict__ ei,
                                               const int* __restrict__ bbase,
                                               const int* __restrict__ blkoff,
                                               unsigned* __restrict__ part,
                                               int nE, int n, int PB, int NB) {
  __shared__ int cur[512];
  int p = blockIdx.x, t = threadIdx.x;
  for (int i = t; i < NB; i += 256) cur[i] = bbase[i] + blkoff[i * PB + p];
  __syncthreads();
  int e0 = p * EPB;
  int e1 = min(e0 + EPB, nE);
  for (int i = e0 + t; i < e1; i += 256) {
    int d = ei[nE + i];
    int s = ei[i];
    if ((unsigned)d < (unsigned)n) {
      int pos = atomicAdd(&cur[d >> 8], 1);
      part[pos] = ((unsigned)s << 8) | (unsigned)(d & 255);
    }
  }
}

__global__ __launch_bounds__(256) void k_bucket(const unsigned* __restrict__ part,
                                                const int* __restrict__ bbase,
                                                int* __restrict__ rowptr,
                                                int* __restrict__ col,
                                                int* __restrict__ deg_arr,
                                                int NB, int n) {
  __shared__ int sdeg[256];
  __shared__ int sscan[256];
  __shared__ int lcol[8448];
  int b = blockIdx.x, t = threadIdx.x;
  int node0 = b * BPB;
  int ebeg = bbase[b];
  int eend = bbase[b + 1];
  int cnt = eend - ebeg;
  if (cnt > 8192) cnt = 8192;
  int nloc = n - node0;
  if (nloc > BPB) nloc = BPB;

  sdeg[t] = (t < nloc) ? 1 : 0;  // self-loop
  __syncthreads();
  for (int i = t; i < cnt; i += 256) {
    int dl = part[ebeg + i] & 255u;
    atomicAdd(&sdeg[dl], 1);
  }
  __syncthreads();
  int v = sdeg[t];
  sscan[t] = v;
  __syncthreads();
  for (int off = 1; off < 256; off <<= 1) {
    int x = (t >= off) ? sscan[t - off] : 0;
    __syncthreads();
    sscan[t] += x;
    __syncthreads();
  }
  int excl = sscan[t] - v;
  int gbase = ebeg + node0;
  if (t < nloc) {
    rowptr[node0 + t] = gbase + excl;
    deg_arr[node0 + t] = v;  // degree incl. self-loop (for degree sort)
  }
  if (b == NB - 1 && t == 0) rowptr[n] = bbase[NB] + n;
  if (t < nloc) lcol[excl] = node0 + t;
  sdeg[t] = excl + 1;
  __syncthreads();
  for (int i = t; i < cnt; i += 256) {
    unsigned e = part[ebeg + i];
    int pos = atomicAdd(&sdeg[e & 255u], 1);
    lcol[pos] = (int)(e >> 8);
  }
  __syncthreads();
  int T = cnt + nloc;
  for (int i = t; i < T; i += 256) col[gbase + i] = lcol[i];
}

// ---------------- degree sort (256-bin counting sort, descending) ----------------
// perf-only: groups equal-degree nodes so agg waves have md ~= deg.
// Any permutation is CORRECT (outputs indexed by node id).
__global__ __launch_bounds__(256) void k_dhist(const int* __restrict__ deg,
                                               int* __restrict__ dbin,
                                               int* __restrict__ dblk, int n, int NBd) {
  __shared__ int hist[256];
  int b = blockIdx.x, t = threadIdx.x;
  hist[t] = 0;
  __syncthreads();
  int i0 = b * DBLK, i1 = min(i0 + DBLK, n);
  for (int i = i0 + t; i < i1; i += 256) atomicAdd(&hist[min(deg[i], 255)], 1);
  __syncthreads();
  int c = hist[t];
  int off = 0;
  if (c) off = atomicAdd(&dbin[t], c);
  dblk[t * NBd + b] = off;
}

__global__ __launch_bounds__(256) void k_dscan(const int* __restrict__ dbin,
                                               int* __restrict__ dbase) {
  __shared__ int s[256];
  int t = threadIdx.x;
  int v = dbin[255 - t];  // descending degree: big bins first
  s[t] = v;
  __syncthreads();
  for (int off = 1; off < 256; off <<= 1) {
    int x = (t >= off) ? s[t - off] : 0;
    __syncthreads();
    s[t] += x;
    __syncthreads();
  }
  dbase[255 - t] = s[t] - v;
}

__global__ __launch_bounds__(256) void k_dscatter(const int* __restrict__ deg,
                                                  const int* __restrict__ dbase,
                                                  const int* __restrict__ dblk,
                                                  int* __restrict__ perm, int n, int NBd) {
  __shared__ int cur[256];
  int b = blockIdx.x, t = threadIdx.x;
  cur[t] = dbase[t] + dblk[t * NBd + b];
  __syncthreads();
  int i0 = b * DBLK, i1 = min(i0 + DBLK, n);
  for (int i = i0 + t; i < i1; i += 256) {
    int pos = atomicAdd(&cur[min(deg[i], 255)], 1);
    perm[pos] = i;
  }
}

// ---------------- MFMA GEMM + fused alpha (fp16 in, fp32 acc) ----------------
// H row-major fp16 (256B rows). mfma_f32_16x16x32_f16; C/D col=lane&15,
// row=quad*4+reg. LDS 16B chunks, chunk j of row r at (j ^ (r&15)) -> <=2-way.
template <typename T>
__global__ __launch_bounds__(256) void k_linear_mfma(const T* __restrict__ X,
                                                     const float* __restrict__ W,
                                                     const float* __restrict__ a_src,
                                                     const float* __restrict__ a_dst,
                                                     __half* __restrict__ H16,
                                                     float* __restrict__ as_,
                                                     float* __restrict__ ad_, int nrows) {
  __shared__ uint4 Xs[64 * 16];   // 16 KB
  __shared__ uint4 Ws[128 * 16];  // 32 KB
  int t = threadIdx.x;
  int row0 = blockIdx.x * 64;

#pragma unroll
  for (int i = 0; i < 4; ++i) {
    int idx = t + i * 256;
    int r = idx >> 4;
    int j = idx & 15;
    uint4 u = make_uint4(0u, 0u, 0u, 0u);
    if (row0 + r < nrows) u = load8h(&X[(size_t)(row0 + r) * 128 + j * 8]);
    Xs[r * 16 + (j ^ (r & 15))] = u;
  }
#pragma unroll
  for (int i = 0; i < 8; ++i) {
    int idx = t + i * 256;
    int c = idx >> 4;
    int j = idx & 15;
    Ws[c * 16 + (j ^ (c & 15))] = load8h(&W[(size_t)c * 128 + j * 8]);
  }
  __syncthreads();

  int w = t >> 6;
  int lane = t & 63;
  int li = lane & 15;
  int quad = lane >> 4;

  v4f acc[8];
#pragma unroll
  for (int ct = 0; ct < 8; ++ct) acc[ct] = (v4f){0.f, 0.f, 0.f, 0.f};

#pragma unroll
  for (int kk = 0; kk < 4; ++kk) {
    int ch = kk * 4 + quad;
    union { uint4 u; v8h h; } av;
    av.u = Xs[(w * 16 + li) * 16 + (ch ^ li)];
#pragma unroll
    for (int ct = 0; ct < 8; ++ct) {
      union { uint4 u; v8h h; } bv;
      bv.u = Ws[(ct * 16 + li) * 16 + (ch ^ li)];
      acc[ct] = __builtin_amdgcn_mfma_f32_16x16x32_f16(av.h, bv.h, acc[ct], 0, 0, 0);
    }
  }

  float asum[4] = {0.f, 0.f, 0.f, 0.f};
  float adsum[4] = {0.f, 0.f, 0.f, 0.f};
#pragma unroll
  for (int ct = 0; ct < 8; ++ct) {
    float sa = a_src[ct * 16 + li];
    float da = a_dst[ct * 16 + li];
#pragma unroll
    for (int reg = 0; reg < 4; ++reg) {
      asum[reg] = fmaf(acc[ct][reg], sa, asum[reg]);
      adsum[reg] = fmaf(acc[ct][reg], da, adsum[reg]);
    }
  }
#pragma unroll
  for (int reg = 0; reg < 4; ++reg) {
    asum[reg] = sum16(asum[reg]);
    adsum[reg] = sum16(adsum[reg]);
  }
  if (li == 0) {
#pragma unroll
    for (int reg = 0; reg < 4; ++reg) {
      int r = row0 + w * 16 + quad * 4 + reg;
      if (r < nrows) {
        as_[r] = asum[reg];
        ad_[r] = adsum[reg];
      }
    }
  }

#pragma unroll
  for (int ct = 0; ct < 8; ++ct) {
#pragma unroll
    for (int reg = 0; reg < 4; ++reg) {
      float v0 = acc[ct][reg];
      float v1 = __shfl_xor(v0, 1);
      if (!(li & 1)) {
        int r = row0 + w * 16 + quad * 4 + reg;
        if (r < nrows) {
          __half2 hh = __floats2half2_rn(v0, v1);
          *(__half2*)&H16[(size_t)r * 128 + ct * 16 + li] = hh;
        }
      }
    }
  }
}

// ---------------- GAT aggregation: 16 lanes/node, 4 nodes/wave, perm order ----------------
#define AGG_SLOT(K, QREG)                                                  \
  if (K == 0 || jj + K < trips) {                                          \
    float wj = __shfl(wgt, gb | (jj + K));                                 \
    uint4 cur = QREG;                                                      \
    if (jj + K + 4 < trips) {                                              \
      int sq = __shfl(s, gb | (jj + K + 4));                               \
      QREG = *(const uint4*)(h + (size_t)sq * 128 + li * 8);               \
    }                                                                      \
    float2 f0 = __half22float2(*(__half2*)&cur.x);                         \
    float2 f1 = __half22float2(*(__half2*)&cur.y);                         \
    float2 f2 = __half22float2(*(__half2*)&cur.z);                         \
    float2 f3 = __half22float2(*(__half2*)&cur.w);                         \
    acc0 = fmaf(f0.x, wj, acc0); acc1 = fmaf(f0.y, wj, acc1);              \
    acc2 = fmaf(f1.x, wj, acc2); acc3 = fmaf(f1.y, wj, acc3);              \
    acc4 = fmaf(f2.x, wj, acc4); acc5 = fmaf(f2.y, wj, acc5);              \
    acc6 = fmaf(f3.x, wj, acc6); acc7 = fmaf(f3.y, wj, acc7);              \
  }

template <bool HEADS>
__global__ __launch_bounds__(256) void k_agg_t(const __half* __restrict__ h,
                                               const float* __restrict__ as_,
                                               const float* __restrict__ ad_,
                                               const int* __restrict__ rowptr,
                                               const int* __restrict__ col,
                                               const int* __restrict__ perm,
                                               const float* __restrict__ bias,
                                               void* __restrict__ outp,
                                               const float* __restrict__ Wf,
                                               const float* __restrict__ bf,
                                               const float* __restrict__ Wsk,
                                               const float* __restrict__ bs,
                                               int n) {
  int gid = blockIdx.x * 256 + threadIdx.x;
  int wid = gid >> 6;
  int lane = gid & 63;
  int g = lane >> 4;
  int li = lane & 15;
  int gb = lane & 48;
  int idx = wid * 4 + g;
  int node = (idx < n) ? perm[idx] : n;
  bool valid = node < n;
  int beg = 0, end = 0;
  float adv = 0.f;
  if (valid) {
    beg = rowptr[node];
    end = rowptr[node + 1];
    adv = ad_[node];
  }
  int deg = end - beg;
  int md = deg;  // wave-max degree (sorted -> nearly equal across groups)
  md = max(md, __shfl_xor(md, 16));
  md = max(md, __shfl_xor(md, 32));

  float acc0 = 0.f, acc1 = 0.f, acc2 = 0.f, acc3 = 0.f;
  float acc4 = 0.f, acc5 = 0.f, acc6 = 0.f, acc7 = 0.f;
  float den_l = 0.f;

  for (int base = 0; base < md; base += 16) {
    int s = 0;
    float wgt = 0.f;
    if (base + li < deg) {
      s = col[beg + base + li];
      if ((unsigned)s >= (unsigned)n) s = 0;
      float v = as_[s] + adv;
      v = (v > 0.f) ? v : 0.2f * v;
      wgt = __expf(v);
    }
    den_l += wgt;

    int rem = md - base;
    int trips = rem > 16 ? 16 : rem;  // wave-uniform
    uint4 q0 = make_uint4(0u, 0u, 0u, 0u);
    uint4 q1 = q0, q2 = q0, q3 = q0;
    {
      int sq = __shfl(s, gb);
      q0 = *(const uint4*)(h + (size_t)sq * 128 + li * 8);
      if (trips > 1) { sq = __shfl(s, gb | 1); q1 = *(const uint4*)(h + (size_t)sq * 128 + li * 8); }
      if (trips > 2) { sq = __shfl(s, gb | 2); q2 = *(const uint4*)(h + (size_t)sq * 128 + li * 8); }
      if (trips > 3) { sq = __shfl(s, gb | 3); q3 = *(const uint4*)(h + (size_t)sq * 128 + li * 8); }
    }
    for (int jj = 0; jj < trips; jj += 4) {
      AGG_SLOT(0, q0)
      AGG_SLOT(1, q1)
      AGG_SLOT(2, q2)
      AGG_SLOT(3, q3)
    }
  }

  float den = sum16(den_l);
  float inv = 1.0f / den;

  float4 bv0 = *(const float4*)&bias[li * 8];
  float4 bv1 = *(const float4*)&bias[li * 8 + 4];
  float o0 = fmaxf(fmaf(acc0, inv, bv0.x), 0.f);
  float o1 = fmaxf(fmaf(acc1, inv, bv0.y), 0.f);
  float o2 = fmaxf(fmaf(acc2, inv, bv0.z), 0.f);
  float o3 = fmaxf(fmaf(acc3, inv, bv0.w), 0.f);
  float o4 = fmaxf(fmaf(acc4, inv, bv1.x), 0.f);
  float o5 = fmaxf(fmaf(acc5, inv, bv1.y), 0.f);
  float o6 = fmaxf(fmaf(acc6, inv, bv1.z), 0.f);
  float o7 = fmaxf(fmaf(acc7, inv, bv1.w), 0.f);

  if (!HEADS) {
    if (valid) {
      union { __half2 h2[4]; uint4 u; } pk;
      pk.h2[0] = __floats2half2_rn(o0, o1);
      pk.h2[1] = __floats2half2_rn(o2, o3);
      pk.h2[2] = __floats2half2_rn(o4, o5);
      pk.h2[3] = __floats2half2_rn(o6, o7);
      *(uint4*)&(((__half*)outp)[(size_t)node * 128 + li * 8]) = pk.u;
    }
  } else {
    float p[10];
#pragma unroll
    for (int j = 0; j < 3; ++j) {
      float4 w0 = *(const float4*)&Wf[(size_t)j * 128 + li * 8];
      float4 w1 = *(const float4*)&Wf[(size_t)j * 128 + li * 8 + 4];
      p[j] = o0 * w0.x + o1 * w0.y + o2 * w0.z + o3 * w0.w +
             o4 * w1.x + o5 * w1.y + o6 * w1.z + o7 * w1.w;
    }
#pragma unroll
    for (int j = 0; j < 7; ++j) {
      float4 w0 = *(const float4*)&Wsk[(size_t)j * 128 + li * 8];
      float4 w1 = *(const float4*)&Wsk[(size_t)j * 128 + li * 8 + 4];
      p[3 + j] = o0 * w0.x + o1 * w0.y + o2 * w0.z + o3 * w0.w +
                 o4 * w1.x + o5 * w1.y + o6 * w1.z + o7 * w1.w;
    }
#pragma unroll
    for (int j = 0; j < 10; ++j) p[j] = sum16(p[j]);
    if (li == 0 && valid) {
      float* out = (float*)outp;
#pragma unroll
      for (int j = 0; j < 3; ++j) out[(size_t)node * 3 + j] = p[j] + bf[j];
      float* sk = out + (size_t)n * 3;
#pragma unroll
      for (int j = 0; j < 7; ++j) sk[(size_t)node * 7 + j] = p[3 + j] + bs[j];
    }
  }
}

// ---------------- launch ----------------
extern "C" void kernel_launch(void* const* d_in, const int* in_sizes, int n_in,
                              void* d_out, int out_size, void* d_ws, size_t ws_size,
                              hipStream_t stream) {
  const float* x = (const float*)d_in[0];
  const int* ei = (const int*)d_in[1];  // [2, E] int32
  const float* W1 = (const float*)d_in[2];
  const float* a_src1 = (const float*)d_in[3];
  const float* a_dst1 = (const float*)d_in[4];
  const float* b1 = (const float*)d_in[5];
  const float* W2 = (const float*)d_in[6];
  const float* a_src2 = (const float*)d_in[7];
  const float* a_dst2 = (const float*)d_in[8];
  const float* b2 = (const float*)d_in[9];
  const float* Wf = (const float*)d_in[10];
  const float* bf = (const float*)d_in[11];
  const float* Wsk = (const float*)d_in[12];
  const float* bs = (const float*)d_in[13];
  float* out = (float*)d_out;

  const int N = in_sizes[0] / 128;
  const int nE = in_sizes[1] / 2;
  const int NB = (N + BPB - 1) / BPB;
  const int PB = (nE + EPB - 1) / EPB;
  const int NCNT = NB * PB;
  const int NBd = (N + DBLK - 1) / DBLK;

  char* w = (char*)d_ws;
  auto carve = [&](size_t bytes) {
    char* p = w;
    w += (bytes + 255) & ~(size_t)255;
    return (void*)p;
  };
  __half* H16 = (__half*)carve((size_t)N * 128 * 2);  // GEMM out (row-major fp16)
  __half* B16 = (__half*)carve((size_t)N * 128 * 2);  // layer-1 agg out
  float* as_ = (float*)carve((size_t)N * 4);
  float* ad_ = (float*)carve((size_t)N * 4);
  int* rowptr = (int*)carve((size_t)(N + 1) * 4);
  int* col = (int*)carve((size_t)(nE + N) * 4);
  int* deg_arr = (int*)carve((size_t)N * 4);
  int* perm = (int*)carve((size_t)N * 4);
  // zeroed region: btot (NB+1) ++ dbin (256)
  int* zeros = (int*)carve((size_t)(NB + 1 + 256) * 4);
  int* btot = zeros;
  int* dbin = zeros + NB + 1;
  int* bbase = (int*)carve((size_t)(NB + 1) * 4);
  int* dbase = (int*)carve(256 * 4);
  int* blkoff = (int*)carve((size_t)NCNT * 4);
  int* dblk = (int*)carve((size_t)256 * NBd * 4);
  unsigned* part = (unsigned*)carve((size_t)nE * 4);  // packed (src<<8)|dloc

  dim3 b256(256);

  // ---- CSR build ----
  hipMemsetAsync(zeros, 0, (size_t)(NB + 1 + 256) * 4, stream);
  k_pcount<<<PB, b256, 0, stream>>>(ei, btot, blkoff, nE, N, PB, NB);
  k_bscan<<<1, b256, 0, stream>>>(btot, bbase, NB);
  k_ppart<<<PB, b256, 0, stream>>>(ei, bbase, blkoff, part, nE, N, PB, NB);
  k_bucket<<<NB, b256, 0, stream>>>(part, bbase, rowptr, col, deg_arr, NB, N);

  // ---- degree sort (perf-only permutation) ----
  k_dhist<<<NBd, b256, 0, stream>>>(deg_arr, dbin, dblk, N, NBd);
  k_dscan<<<1, b256, 0, stream>>>(dbin, dbase);
  k_dscatter<<<NBd, b256, 0, stream>>>(deg_arr, dbase, dblk, perm, N, NBd);

  const int gemm_blocks = (N + 63) / 64;
  const int agg_blocks = (((N + 3) / 4) * 64 + 255) / 256;  // 4 nodes/wave

  // ---- layer 1 ----
  k_linear_mfma<float><<<gemm_blocks, b256, 0, stream>>>(x, W1, a_src1, a_dst1, H16, as_, ad_, N);
  k_agg_t<false><<<agg_blocks, b256, 0, stream>>>(H16, as_, ad_, rowptr, col, perm, b1, B16,
                                                  nullptr, nullptr, nullptr, nullptr, N);

  // ---- layer 2 + fused heads ----
  k_linear_mfma<__half><<<gemm_blocks, b256, 0, stream>>>(B16, W2, a_src2, a_dst2, H16, as_, ad_, N);
  k_agg_t<true><<<agg_blocks, b256, 0, stream>>>(H16, as_, ad_, rowptr, col, perm, b2, out,
                                                 Wf, bf, Wsk, bs, N);
}

// Round 11
// 340.993 us; speedup vs baseline: 1.3203x; 1.0265x over previous
//
#include <hip/hip_runtime.h>
#include <hip/hip_bf16.h>
#include <hip/hip_fp16.h>
#include <math.h>

#define EPB 8192   // edges per partition block
#define BPB 256    // nodes per bucket

typedef _Float16 v8h __attribute__((ext_vector_type(8)));
typedef float v4f __attribute__((ext_vector_type(4)));

// ---------------- wave helpers (wave = 64 on gfx950) ----------------
__device__ inline float sum16(float v) {  // reduce within 16-lane groups
#pragma unroll
  for (int off = 1; off < 16; off <<= 1) v += __shfl_xor(v, off);
  return v;
}

// load 8 consecutive values as 8 halves (16B)
__device__ inline uint4 load8h(const float* p) {
  float4 a = *(const float4*)p;
  float4 b = *(const float4*)(p + 4);
  union { __half2 h[4]; uint4 u; } pk;
  pk.h[0] = __floats2half2_rn(a.x, a.y);
  pk.h[1] = __floats2half2_rn(a.z, a.w);
  pk.h[2] = __floats2half2_rn(b.x, b.y);
  pk.h[3] = __floats2half2_rn(b.z, b.w);
  return pk.u;
}
__device__ inline uint4 load8h(const __half* p) { return *(const uint4*)p; }

// ---------------- in-block inclusive scan of btot[0..NB), NB <= 512 ----------------
// Hillis-Steele over 512 slots, ping-pong buffers sA/sB (each int[512]).
// Returns pointer to the buffer holding the inclusive scan.
__device__ inline int* scan_inc512(const int* __restrict__ btot, int NB, int t,
                                   int* sA, int* sB) {
#pragma unroll
  for (int i = t; i < 512; i += 256) sA[i] = (i < NB) ? btot[i] : 0;
  __syncthreads();
  int* src = sA;
  int* dst = sB;
  for (int off = 1; off < 512; off <<= 1) {
#pragma unroll
    for (int i = t; i < 512; i += 256) {
      int v = src[i];
      if (i >= off) v += src[i - off];
      dst[i] = v;
    }
    __syncthreads();
    int* tmp = src; src = dst; dst = tmp;
  }
  return src;  // inclusive scan, all writes visible
}

// ---------------- pcount body (per-block histogram + global offset reserve) ----------------
__device__ inline void pcount_body(const int* __restrict__ ei, int* __restrict__ btot,
                                   int* __restrict__ blkoff, int* hist,
                                   int p, int t, int nE, int n, int PB, int NB) {
  for (int i = t; i < NB; i += 256) hist[i] = 0;
  __syncthreads();
  int e0 = p * EPB;
  int e1 = min(e0 + EPB, nE);
  for (int i = e0 + t; i < e1; i += 256) {
    int d = ei[nE + i];
    if ((unsigned)d < (unsigned)n) atomicAdd(&hist[d >> 8], 1);
  }
  __syncthreads();
  for (int i = t; i < NB; i += 256) {
    int h = hist[i];
    int off = atomicAdd(&btot[i], h);
    blkoff[i * PB + p] = off;
  }
}

// ---------------- GEMM tile body: MFMA fp16, fused alpha ----------------
// H row-major fp16 (256B rows). mfma_f32_16x16x32_f16; C/D col=lane&15,
// row=quad*4+reg. LDS 16B chunks, chunk j of row r at (j ^ (r&15)) -> <=2-way.
template <typename T>
__device__ inline void gemm_tile(uint4* Xs, uint4* Ws, int t, int row0,
                                 const T* __restrict__ X, const float* __restrict__ W,
                                 const float* __restrict__ a_src,
                                 const float* __restrict__ a_dst,
                                 __half* __restrict__ H16,
                                 float* __restrict__ as_, float* __restrict__ ad_,
                                 int nrows) {
#pragma unroll
  for (int i = 0; i < 4; ++i) {
    int idx = t + i * 256;
    int r = idx >> 4;
    int j = idx & 15;
    uint4 u = make_uint4(0u, 0u, 0u, 0u);
    if (row0 + r < nrows) u = load8h(&X[(size_t)(row0 + r) * 128 + j * 8]);
    Xs[r * 16 + (j ^ (r & 15))] = u;
  }
#pragma unroll
  for (int i = 0; i < 8; ++i) {
    int idx = t + i * 256;
    int c = idx >> 4;
    int j = idx & 15;
    Ws[c * 16 + (j ^ (c & 15))] = load8h(&W[(size_t)c * 128 + j * 8]);
  }
  __syncthreads();

  int w = t >> 6;
  int lane = t & 63;
  int li = lane & 15;
  int quad = lane >> 4;

  v4f acc[8];
#pragma unroll
  for (int ct = 0; ct < 8; ++ct) acc[ct] = (v4f){0.f, 0.f, 0.f, 0.f};

#pragma unroll
  for (int kk = 0; kk < 4; ++kk) {
    int ch = kk * 4 + quad;
    union { uint4 u; v8h h; } av;
    av.u = Xs[(w * 16 + li) * 16 + (ch ^ li)];
#pragma unroll
    for (int ct = 0; ct < 8; ++ct) {
      union { uint4 u; v8h h; } bv;
      bv.u = Ws[(ct * 16 + li) * 16 + (ch ^ li)];
      acc[ct] = __builtin_amdgcn_mfma_f32_16x16x32_f16(av.h, bv.h, acc[ct], 0, 0, 0);
    }
  }

  float asum[4] = {0.f, 0.f, 0.f, 0.f};
  float adsum[4] = {0.f, 0.f, 0.f, 0.f};
#pragma unroll
  for (int ct = 0; ct < 8; ++ct) {
    float sa = a_src[ct * 16 + li];
    float da = a_dst[ct * 16 + li];
#pragma unroll
    for (int reg = 0; reg < 4; ++reg) {
      asum[reg] = fmaf(acc[ct][reg], sa, asum[reg]);
      adsum[reg] = fmaf(acc[ct][reg], da, adsum[reg]);
    }
  }
#pragma unroll
  for (int reg = 0; reg < 4; ++reg) {
    asum[reg] = sum16(asum[reg]);
    adsum[reg] = sum16(adsum[reg]);
  }
  if (li == 0) {
#pragma unroll
    for (int reg = 0; reg < 4; ++reg) {
      int r = row0 + w * 16 + quad * 4 + reg;
      if (r < nrows) {
        as_[r] = asum[reg];
        ad_[r] = adsum[reg];
      }
    }
  }

#pragma unroll
  for (int ct = 0; ct < 8; ++ct) {
#pragma unroll
    for (int reg = 0; reg < 4; ++reg) {
      float v0 = acc[ct][reg];
      float v1 = __shfl_xor(v0, 1);
      if (!(li & 1)) {
        int r = row0 + w * 16 + quad * 4 + reg;
        if (r < nrows) {
          __half2 hh = __floats2half2_rn(v0, v1);
          *(__half2*)&H16[(size_t)r * 128 + ct * 16 + li] = hh;
        }
      }
    }
  }
}

// ---------------- fused: pcount blocks [0,PB) || layer-1 GEMM blocks [PB,..) ----------------
__global__ __launch_bounds__(256) void k_fused1(const int* __restrict__ ei,
                                                int* __restrict__ btot,
                                                int* __restrict__ blkoff,
                                                int nE, int n, int PB, int NB,
                                                const float* __restrict__ X,
                                                const float* __restrict__ W,
                                                const float* __restrict__ a_src,
                                                const float* __restrict__ a_dst,
                                                __half* __restrict__ H16,
                                                float* __restrict__ as_,
                                                float* __restrict__ ad_) {
  __shared__ __align__(16) char smraw[48 * 1024];
  int t = threadIdx.x;
  if ((int)blockIdx.x < PB) {
    pcount_body(ei, btot, blkoff, (int*)smraw, blockIdx.x, t, nE, n, PB, NB);
  } else {
    uint4* Xs = (uint4*)smraw;             // 16 KB
    uint4* Ws = (uint4*)(smraw + 16384);   // 32 KB
    int row0 = (blockIdx.x - PB) * 64;
    gemm_tile<float>(Xs, Ws, t, row0, X, W, a_src, a_dst, H16, as_, ad_, n);
  }
}

// ---------------- standalone layer-2 GEMM ----------------
__global__ __launch_bounds__(256) void k_linear2(const __half* __restrict__ X,
                                                 const float* __restrict__ W,
                                                 const float* __restrict__ a_src,
                                                 const float* __restrict__ a_dst,
                                                 __half* __restrict__ H16,
                                                 float* __restrict__ as_,
                                                 float* __restrict__ ad_, int nrows) {
  __shared__ __align__(16) char smraw[48 * 1024];
  uint4* Xs = (uint4*)smraw;
  uint4* Ws = (uint4*)(smraw + 16384);
  gemm_tile<__half>(Xs, Ws, threadIdx.x, blockIdx.x * 64, X, W, a_src, a_dst,
                    H16, as_, ad_, nrows);
}

// ---------------- ppart: scatter packed (src<<8)|dloc into reserved slots ----------------
__global__ __launch_bounds__(256) void k_ppart(const int* __restrict__ ei,
                                               const int* __restrict__ btot,
                                               const int* __restrict__ blkoff,
                                               unsigned* __restrict__ part,
                                               int nE, int n, int PB, int NB) {
  __shared__ int sA[512], sB[512];
  __shared__ int cur[512];
  int p = blockIdx.x, t = threadIdx.x;
  int* inc = scan_inc512(btot, NB, t, sA, sB);
  for (int i = t; i < NB; i += 256) {
    int excl = (i == 0) ? 0 : inc[i - 1];
    cur[i] = excl + blkoff[i * PB + p];
  }
  __syncthreads();
  int e0 = p * EPB;
  int e1 = min(e0 + EPB, nE);
  for (int i = e0 + t; i < e1; i += 256) {
    int d = ei[nE + i];
    int s = ei[i];
    if ((unsigned)d < (unsigned)n) {
      int pos = atomicAdd(&cur[d >> 8], 1);
      part[pos] = ((unsigned)s << 8) | (unsigned)(d & 255);
    }
  }
}

// ---------------- bucket: build 256-node CSR in LDS, write coalesced ----------------
__global__ __launch_bounds__(256) void k_bucket(const unsigned* __restrict__ part,
                                                const int* __restrict__ btot,
                                                int* __restrict__ rowptr,
                                                int* __restrict__ col,
                                                int NB, int n) {
  __shared__ int sdeg[256];
  __shared__ int sscan[256];
  __shared__ int lcol[8448];
  int b = blockIdx.x, t = threadIdx.x;
  int node0 = b * BPB;
  // recompute bucket bases from btot (reuse lcol as scan scratch)
  int* inc = scan_inc512(btot, NB, t, lcol, lcol + 512);
  int ebeg = (b == 0) ? 0 : inc[b - 1];
  int eend = inc[b];
  int total = inc[NB - 1];
  __syncthreads();  // done with scan scratch before lcol reuse

  int cnt = eend - ebeg;
  if (cnt > 8192) cnt = 8192;  // >60-sigma guard
  int nloc = n - node0;
  if (nloc > BPB) nloc = BPB;

  sdeg[t] = (t < nloc) ? 1 : 0;  // self-loop
  __syncthreads();
  for (int i = t; i < cnt; i += 256) {
    int dl = part[ebeg + i] & 255u;
    atomicAdd(&sdeg[dl], 1);
  }
  __syncthreads();
  int v = sdeg[t];
  sscan[t] = v;
  __syncthreads();
  for (int off = 1; off < 256; off <<= 1) {
    int x = (t >= off) ? sscan[t - off] : 0;
    __syncthreads();
    sscan[t] += x;
    __syncthreads();
  }
  int excl = sscan[t] - v;
  int gbase = ebeg + node0;
  if (t < nloc) rowptr[node0 + t] = gbase + excl;
  if (b == NB - 1 && t == 0) rowptr[n] = total + n;
  if (t < nloc) lcol[excl] = node0 + t;
  sdeg[t] = excl + 1;
  __syncthreads();
  for (int i = t; i < cnt; i += 256) {
    unsigned e = part[ebeg + i];
    int pos = atomicAdd(&sdeg[e & 255u], 1);
    lcol[pos] = (int)(e >> 8);
  }
  __syncthreads();
  int T = cnt + nloc;
  for (int i = t; i < T; i += 256) col[gbase + i] = lcol[i];
}

// ---------------- GAT aggregation: 16 lanes/node, 4 nodes/wave ----------------
#define AGG_SLOT(K, QREG)                                                  \
  if (K == 0 || jj + K < trips) {                                          \
    float wj = __shfl(wgt, gb | (jj + K));                                 \
    uint4 cur = QREG;                                                      \
    if (jj + K + 4 < trips) {                                              \
      int sq = __shfl(s, gb | (jj + K + 4));                               \
      QREG = *(const uint4*)(h + (size_t)sq * 128 + li * 8);               \
    }                                                                      \
    float2 f0 = __half22float2(*(__half2*)&cur.x);                         \
    float2 f1 = __half22float2(*(__half2*)&cur.y);                         \
    float2 f2 = __half22float2(*(__half2*)&cur.z);                         \
    float2 f3 = __half22float2(*(__half2*)&cur.w);                         \
    acc0 = fmaf(f0.x, wj, acc0); acc1 = fmaf(f0.y, wj, acc1);              \
    acc2 = fmaf(f1.x, wj, acc2); acc3 = fmaf(f1.y, wj, acc3);              \
    acc4 = fmaf(f2.x, wj, acc4); acc5 = fmaf(f2.y, wj, acc5);              \
    acc6 = fmaf(f3.x, wj, acc6); acc7 = fmaf(f3.y, wj, acc7);              \
  }

template <bool HEADS>
__global__ __launch_bounds__(256) void k_agg_t(const __half* __restrict__ h,
                                               const float* __restrict__ as_,
                                               const float* __restrict__ ad_,
                                               const int* __restrict__ rowptr,
                                               const int* __restrict__ col,
                                               const float* __restrict__ bias,
                                               void* __restrict__ outp,
                                               const float* __restrict__ Wf,
                                               const float* __restrict__ bf,
                                               const float* __restrict__ Wsk,
                                               const float* __restrict__ bs,
                                               int n) {
  int gid = blockIdx.x * 256 + threadIdx.x;
  int wid = gid >> 6;
  int lane = gid & 63;
  int g = lane >> 4;
  int li = lane & 15;
  int gb = lane & 48;
  int node = wid * 4 + g;
  bool valid = node < n;
  int beg = 0, end = 0;
  float adv = 0.f;
  if (valid) {
    beg = rowptr[node];
    end = rowptr[node + 1];
    adv = ad_[node];
  }
  int deg = end - beg;
  int md = deg;
  md = max(md, __shfl_xor(md, 16));
  md = max(md, __shfl_xor(md, 32));

  float acc0 = 0.f, acc1 = 0.f, acc2 = 0.f, acc3 = 0.f;
  float acc4 = 0.f, acc5 = 0.f, acc6 = 0.f, acc7 = 0.f;
  float den_l = 0.f;

  for (int base = 0; base < md; base += 16) {
    int s = 0;
    float wgt = 0.f;
    if (base + li < deg) {
      s = col[beg + base + li];
      if ((unsigned)s >= (unsigned)n) s = 0;
      float v = as_[s] + adv;
      v = (v > 0.f) ? v : 0.2f * v;
      wgt = __expf(v);
    }
    den_l += wgt;

    int rem = md - base;
    int trips = rem > 16 ? 16 : rem;  // wave-uniform
    uint4 q0 = make_uint4(0u, 0u, 0u, 0u);
    uint4 q1 = q0, q2 = q0, q3 = q0;
    {
      int sq = __shfl(s, gb);
      q0 = *(const uint4*)(h + (size_t)sq * 128 + li * 8);
      if (trips > 1) { sq = __shfl(s, gb | 1); q1 = *(const uint4*)(h + (size_t)sq * 128 + li * 8); }
      if (trips > 2) { sq = __shfl(s, gb | 2); q2 = *(const uint4*)(h + (size_t)sq * 128 + li * 8); }
      if (trips > 3) { sq = __shfl(s, gb | 3); q3 = *(const uint4*)(h + (size_t)sq * 128 + li * 8); }
    }
    for (int jj = 0; jj < trips; jj += 4) {
      AGG_SLOT(0, q0)
      AGG_SLOT(1, q1)
      AGG_SLOT(2, q2)
      AGG_SLOT(3, q3)
    }
  }

  float den = sum16(den_l);
  float inv = 1.0f / den;

  float4 bv0 = *(const float4*)&bias[li * 8];
  float4 bv1 = *(const float4*)&bias[li * 8 + 4];
  float o0 = fmaxf(fmaf(acc0, inv, bv0.x), 0.f);
  float o1 = fmaxf(fmaf(acc1, inv, bv0.y), 0.f);
  float o2 = fmaxf(fmaf(acc2, inv, bv0.z), 0.f);
  float o3 = fmaxf(fmaf(acc3, inv, bv0.w), 0.f);
  float o4 = fmaxf(fmaf(acc4, inv, bv1.x), 0.f);
  float o5 = fmaxf(fmaf(acc5, inv, bv1.y), 0.f);
  float o6 = fmaxf(fmaf(acc6, inv, bv1.z), 0.f);
  float o7 = fmaxf(fmaf(acc7, inv, bv1.w), 0.f);

  if (!HEADS) {
    if (valid) {
      union { __half2 h2[4]; uint4 u; } pk;
      pk.h2[0] = __floats2half2_rn(o0, o1);
      pk.h2[1] = __floats2half2_rn(o2, o3);
      pk.h2[2] = __floats2half2_rn(o4, o5);
      pk.h2[3] = __floats2half2_rn(o6, o7);
      *(uint4*)&(((__half*)outp)[(size_t)node * 128 + li * 8]) = pk.u;
    }
  } else {
    float p[10];
#pragma unroll
    for (int j = 0; j < 3; ++j) {
      float4 w0 = *(const float4*)&Wf[(size_t)j * 128 + li * 8];
      float4 w1 = *(const float4*)&Wf[(size_t)j * 128 + li * 8 + 4];
      p[j] = o0 * w0.x + o1 * w0.y + o2 * w0.z + o3 * w0.w +
             o4 * w1.x + o5 * w1.y + o6 * w1.z + o7 * w1.w;
    }
#pragma unroll
    for (int j = 0; j < 7; ++j) {
      float4 w0 = *(const float4*)&Wsk[(size_t)j * 128 + li * 8];
      float4 w1 = *(const float4*)&Wsk[(size_t)j * 128 + li * 8 + 4];
      p[3 + j] = o0 * w0.x + o1 * w0.y + o2 * w0.z + o3 * w0.w +
                 o4 * w1.x + o5 * w1.y + o6 * w1.z + o7 * w1.w;
    }
#pragma unroll
    for (int j = 0; j < 10; ++j) p[j] = sum16(p[j]);
    if (li == 0 && valid) {
      float* out = (float*)outp;
#pragma unroll
      for (int j = 0; j < 3; ++j) out[(size_t)node * 3 + j] = p[j] + bf[j];
      float* sk = out + (size_t)n * 3;
#pragma unroll
      for (int j = 0; j < 7; ++j) sk[(size_t)node * 7 + j] = p[3 + j] + bs[j];
    }
  }
}

// ---------------- launch ----------------
extern "C" void kernel_launch(void* const* d_in, const int* in_sizes, int n_in,
                              void* d_out, int out_size, void* d_ws, size_t ws_size,
                              hipStream_t stream) {
  const float* x = (const float*)d_in[0];
  const int* ei = (const int*)d_in[1];  // [2, E] int32
  const float* W1 = (const float*)d_in[2];
  const float* a_src1 = (const float*)d_in[3];
  const float* a_dst1 = (const float*)d_in[4];
  const float* b1 = (const float*)d_in[5];
  const float* W2 = (const float*)d_in[6];
  const float* a_src2 = (const float*)d_in[7];
  const float* a_dst2 = (const float*)d_in[8];
  const float* b2 = (const float*)d_in[9];
  const float* Wf = (const float*)d_in[10];
  const float* bf = (const float*)d_in[11];
  const float* Wsk = (const float*)d_in[12];
  const float* bs = (const float*)d_in[13];
  float* out = (float*)d_out;

  const int N = in_sizes[0] / 128;
  const int nE = in_sizes[1] / 2;
  const int NB = (N + BPB - 1) / BPB;   // buckets, <=512
  const int PB = (nE + EPB - 1) / EPB;  // partition blocks
  const int NCNT = NB * PB;

  char* w = (char*)d_ws;
  auto carve = [&](size_t bytes) {
    char* p = w;
    w += (bytes + 255) & ~(size_t)255;
    return (void*)p;
  };
  __half* H16 = (__half*)carve((size_t)N * 128 * 2);  // GEMM out (row-major fp16)
  __half* B16 = (__half*)carve((size_t)N * 128 * 2);  // layer-1 agg out
  float* as_ = (float*)carve((size_t)N * 4);
  float* ad_ = (float*)carve((size_t)N * 4);
  int* rowptr = (int*)carve((size_t)(N + 1) * 4);
  int* col = (int*)carve((size_t)(nE + N) * 4);
  int* btot = (int*)carve((size_t)(NB + 1) * 4);
  int* blkoff = (int*)carve((size_t)NCNT * 4);
  unsigned* part = (unsigned*)carve((size_t)nE * 4);  // packed (src<<8)|dloc

  dim3 b256(256);
  const int gemm_blocks = (N + 63) / 64;
  const int agg_blocks = (((N + 3) / 4) * 64 + 255) / 256;  // 4 nodes/wave

  // ---- CSR build (pcount fused with layer-1 GEMM: independent work) ----
  hipMemsetAsync(btot, 0, (size_t)(NB + 1) * 4, stream);
  k_fused1<<<PB + gemm_blocks, b256, 0, stream>>>(ei, btot, blkoff, nE, N, PB, NB,
                                                  x, W1, a_src1, a_dst1, H16, as_, ad_);
  k_ppart<<<PB, b256, 0, stream>>>(ei, btot, blkoff, part, nE, N, PB, NB);
  k_bucket<<<NB, b256, 0, stream>>>(part, btot, rowptr, col, NB, N);

  // ---- layer 1 aggregation ----
  k_agg_t<false><<<agg_blocks, b256, 0, stream>>>(H16, as_, ad_, rowptr, col, b1, B16,
                                                  nullptr, nullptr, nullptr, nullptr, N);

  // ---- layer 2 + fused heads ----
  k_linear2<<<gemm_blocks, b256, 0, stream>>>(B16, W2, a_src2, a_dst2, H16, as_, ad_, N);
  k_agg_t<true><<<agg_blocks, b256, 0, stream>>>(H16, as_, ad_, rowptr, col, b2, out,
                                                 Wf, bf, Wsk, bs, N);
}

// Round 12
// 326.031 us; speedup vs baseline: 1.3808x; 1.0459x over previous
//
#include <hip/hip_runtime.h>
#include <hip/hip_bf16.h>
#include <hip/hip_fp16.h>
#include <math.h>

#define EPB 8192   // edges per partition block (PB = ceil(nE/EPB) must be <= 256)
#define BPB 256    // nodes per bucket (NB <= 512)

typedef _Float16 v8h __attribute__((ext_vector_type(8)));
typedef float v4f __attribute__((ext_vector_type(4)));

// ---------------- wave helpers (wave = 64 on gfx950) ----------------
__device__ inline float sum16(float v) {  // reduce within 16-lane groups
#pragma unroll
  for (int off = 1; off < 16; off <<= 1) v += __shfl_xor(v, off);
  return v;
}

// load 8 consecutive values as 8 halves (16B)
__device__ inline uint4 load8h(const float* p) {
  float4 a = *(const float4*)p;
  float4 b = *(const float4*)(p + 4);
  union { __half2 h[4]; uint4 u; } pk;
  pk.h[0] = __floats2half2_rn(a.x, a.y);
  pk.h[1] = __floats2half2_rn(a.z, a.w);
  pk.h[2] = __floats2half2_rn(b.x, b.y);
  pk.h[3] = __floats2half2_rn(b.z, b.w);
  return pk.u;
}
__device__ inline uint4 load8h(const __half* p) { return *(const uint4*)p; }

// ---------------- partition body: block-local hist + scan + counting sort ----------------
// Fully block-local: no global atomics. Writes lexcl row (NB+1 ints) to
// blkoff[p*(NB+1)+i] and the bucket-sorted packed edges ((src<<8)|dloc) to
// part[p*EPB ...] as ONE coalesced stream.
__device__ inline void psort_body(const int* __restrict__ ei, int* __restrict__ blkoff,
                                  unsigned* __restrict__ part, char* smraw,
                                  int p, int t, int nE, int n, int NB) {
  int* hist = (int*)smraw;          // 512
  int* sA = hist + 512;             // 512
  int* sB = sA + 512;               // 512
  int* cur = sB + 512;              // 512
  unsigned* buf = (unsigned*)(cur + 512);  // 8192 (32 KB) -> total 40 KB

  for (int i = t; i < 512; i += 256) hist[i] = 0;
  __syncthreads();
  int e0 = p * EPB;
  int e1 = min(e0 + EPB, nE);
  for (int i = e0 + t; i < e1; i += 256) {
    int d = ei[nE + i];
    if ((unsigned)d < (unsigned)n) atomicAdd(&hist[d >> 8], 1);
  }
  __syncthreads();
  // inclusive scan over 512 slots (ping-pong)
  for (int i = t; i < 512; i += 256) sA[i] = hist[i];
  __syncthreads();
  int* src = sA;
  int* dst = sB;
  for (int off = 1; off < 512; off <<= 1) {
    for (int i = t; i < 512; i += 256) {
      int v = src[i];
      if (i >= off) v += src[i - off];
      dst[i] = v;
    }
    __syncthreads();
    int* tmp = src; src = dst; dst = tmp;
  }
  // src = inclusive scan. write lexcl row + init cursors
  int* bo = blkoff + (size_t)p * (NB + 1);
  for (int i = t; i < NB; i += 256) {
    int excl = (i == 0) ? 0 : src[i - 1];
    bo[i] = excl;
    cur[i] = excl;
  }
  if (t == 0) bo[NB] = src[NB - 1];
  __syncthreads();
  // counting-sort scatter into LDS buf
  for (int i = e0 + t; i < e1; i += 256) {
    int d = ei[nE + i];
    int s = ei[i];
    if ((unsigned)d < (unsigned)n) {
      int pos = atomicAdd(&cur[d >> 8], 1);
      buf[pos] = ((unsigned)s << 8) | (unsigned)(d & 255);
    }
  }
  __syncthreads();
  int cnt = src[NB - 1];
  for (int i = t; i < cnt; i += 256) part[e0 + i] = buf[i];
}

// ---------------- GEMM tile body: MFMA fp16, fused alpha ----------------
// H row-major fp16 (256B rows). mfma_f32_16x16x32_f16; C/D col=lane&15,
// row=quad*4+reg. LDS 16B chunks, chunk j of row r at (j ^ (r&15)) -> <=2-way.
template <typename T>
__device__ inline void gemm_tile(uint4* Xs, uint4* Ws, int t, int row0,
                                 const T* __restrict__ X, const float* __restrict__ W,
                                 const float* __restrict__ a_src,
                                 const float* __restrict__ a_dst,
                                 __half* __restrict__ H16,
                                 float* __restrict__ as_, float* __restrict__ ad_,
                                 int nrows) {
#pragma unroll
  for (int i = 0; i < 4; ++i) {
    int idx = t + i * 256;
    int r = idx >> 4;
    int j = idx & 15;
    uint4 u = make_uint4(0u, 0u, 0u, 0u);
    if (row0 + r < nrows) u = load8h(&X[(size_t)(row0 + r) * 128 + j * 8]);
    Xs[r * 16 + (j ^ (r & 15))] = u;
  }
#pragma unroll
  for (int i = 0; i < 8; ++i) {
    int idx = t + i * 256;
    int c = idx >> 4;
    int j = idx & 15;
    Ws[c * 16 + (j ^ (c & 15))] = load8h(&W[(size_t)c * 128 + j * 8]);
  }
  __syncthreads();

  int w = t >> 6;
  int lane = t & 63;
  int li = lane & 15;
  int quad = lane >> 4;

  v4f acc[8];
#pragma unroll
  for (int ct = 0; ct < 8; ++ct) acc[ct] = (v4f){0.f, 0.f, 0.f, 0.f};

#pragma unroll
  for (int kk = 0; kk < 4; ++kk) {
    int ch = kk * 4 + quad;
    union { uint4 u; v8h h; } av;
    av.u = Xs[(w * 16 + li) * 16 + (ch ^ li)];
#pragma unroll
    for (int ct = 0; ct < 8; ++ct) {
      union { uint4 u; v8h h; } bv;
      bv.u = Ws[(ct * 16 + li) * 16 + (ch ^ li)];
      acc[ct] = __builtin_amdgcn_mfma_f32_16x16x32_f16(av.h, bv.h, acc[ct], 0, 0, 0);
    }
  }

  float asum[4] = {0.f, 0.f, 0.f, 0.f};
  float adsum[4] = {0.f, 0.f, 0.f, 0.f};
#pragma unroll
  for (int ct = 0; ct < 8; ++ct) {
    float sa = a_src[ct * 16 + li];
    float da = a_dst[ct * 16 + li];
#pragma unroll
    for (int reg = 0; reg < 4; ++reg) {
      asum[reg] = fmaf(acc[ct][reg], sa, asum[reg]);
      adsum[reg] = fmaf(acc[ct][reg], da, adsum[reg]);
    }
  }
#pragma unroll
  for (int reg = 0; reg < 4; ++reg) {
    asum[reg] = sum16(asum[reg]);
    adsum[reg] = sum16(adsum[reg]);
  }
  if (li == 0) {
#pragma unroll
    for (int reg = 0; reg < 4; ++reg) {
      int r = row0 + w * 16 + quad * 4 + reg;
      if (r < nrows) {
        as_[r] = asum[reg];
        ad_[r] = adsum[reg];
      }
    }
  }

#pragma unroll
  for (int ct = 0; ct < 8; ++ct) {
#pragma unroll
    for (int reg = 0; reg < 4; ++reg) {
      float v0 = acc[ct][reg];
      float v1 = __shfl_xor(v0, 1);
      if (!(li & 1)) {
        int r = row0 + w * 16 + quad * 4 + reg;
        if (r < nrows) {
          __half2 hh = __floats2half2_rn(v0, v1);
          *(__half2*)&H16[(size_t)r * 128 + ct * 16 + li] = hh;
        }
      }
    }
  }
}

// ---------------- fused: partition blocks [0,PB) || layer-1 GEMM blocks [PB,..) ----------------
__global__ __launch_bounds__(256) void k_fused1(const int* __restrict__ ei,
                                                int* __restrict__ blkoff,
                                                unsigned* __restrict__ part,
                                                int nE, int n, int PB, int NB,
                                                const float* __restrict__ X,
                                                const float* __restrict__ W,
                                                const float* __restrict__ a_src,
                                                const float* __restrict__ a_dst,
                                                __half* __restrict__ H16,
                                                float* __restrict__ as_,
                                                float* __restrict__ ad_) {
  __shared__ __align__(16) char smraw[48 * 1024];
  int t = threadIdx.x;
  if ((int)blockIdx.x < PB) {
    psort_body(ei, blkoff, part, smraw, blockIdx.x, t, nE, n, NB);
  } else {
    uint4* Xs = (uint4*)smraw;            // 16 KB
    uint4* Ws = (uint4*)(smraw + 16384);  // 32 KB
    int row0 = (blockIdx.x - PB) * 64;
    gemm_tile<float>(Xs, Ws, t, row0, X, W, a_src, a_dst, H16, as_, ad_, n);
  }
}

// ---------------- standalone layer-2 GEMM ----------------
__global__ __launch_bounds__(256) void k_linear2(const __half* __restrict__ X,
                                                 const float* __restrict__ W,
                                                 const float* __restrict__ a_src,
                                                 const float* __restrict__ a_dst,
                                                 __half* __restrict__ H16,
                                                 float* __restrict__ as_,
                                                 float* __restrict__ ad_, int nrows) {
  __shared__ __align__(16) char smraw[48 * 1024];
  uint4* Xs = (uint4*)smraw;
  uint4* Ws = (uint4*)(smraw + 16384);
  gemm_tile<__half>(Xs, Ws, threadIdx.x, blockIdx.x * 64, X, W, a_src, a_dst,
                    H16, as_, ad_, nrows);
}

// ---------------- bucket: gather per-block runs, build CSR in LDS, write coalesced ----------------
// ebeg[b] = sum_p lexcl[p][b]; run of block p = part[p*EPB + lexcl[p][b] .. +lexcl[p][b+1]).
__global__ __launch_bounds__(256) void k_bucket(const unsigned* __restrict__ part,
                                                const int* __restrict__ blkoff,
                                                int* __restrict__ rowptr,
                                                int* __restrict__ col,
                                                int PB, int NB, int n) {
  __shared__ int sdeg[256];
  __shared__ int sscan[256];
  __shared__ int pbeg[256];
  __shared__ int pend[256];
  __shared__ int red[256];
  __shared__ int lcol[8448];
  int b = blockIdx.x, t = threadIdx.x;
  int node0 = b * BPB;

  int lb = 0, le = 0;
  if (t < PB) {
    lb = blkoff[(size_t)t * (NB + 1) + b];
    le = blkoff[(size_t)t * (NB + 1) + b + 1];
  }
  pbeg[t] = lb;
  pend[t] = le;
  // reduce: ebeg = sum lb; cnt = sum (le-lb)
  red[t] = lb;
  __syncthreads();
  for (int off = 128; off; off >>= 1) {
    if (t < off) red[t] += red[t + off];
    __syncthreads();
  }
  int ebeg = red[0];
  __syncthreads();
  red[t] = le - lb;
  __syncthreads();
  for (int off = 128; off; off >>= 1) {
    if (t < off) red[t] += red[t + off];
    __syncthreads();
  }
  int cnt = red[0];
  __syncthreads();
  if (cnt > 8192) cnt = 8192;  // >60-sigma guard (never triggers)

  int nloc = n - node0;
  if (nloc > BPB) nloc = BPB;

  sdeg[t] = (t < nloc) ? 1 : 0;  // self-loop
  __syncthreads();
  if (t < PB) {
    const unsigned* base = part + (size_t)t * EPB;
    for (int j = pbeg[t]; j < pend[t]; ++j) atomicAdd(&sdeg[base[j] & 255u], 1);
  }
  __syncthreads();
  int v = sdeg[t];
  sscan[t] = v;
  __syncthreads();
  for (int off = 1; off < 256; off <<= 1) {
    int x = (t >= off) ? sscan[t - off] : 0;
    __syncthreads();
    sscan[t] += x;
    __syncthreads();
  }
  int excl = sscan[t] - v;
  int gbase = ebeg + node0;
  if (t < nloc) rowptr[node0 + t] = gbase + excl;
  if (b == NB - 1 && t == 0) rowptr[n] = ebeg + cnt + n;
  if (t < nloc) lcol[excl] = node0 + t;  // self-loop entry first
  sdeg[t] = excl + 1;                    // cursor
  __syncthreads();
  if (t < PB) {
    const unsigned* base = part + (size_t)t * EPB;
    for (int j = pbeg[t]; j < pend[t]; ++j) {
      unsigned e = base[j];
      int pos = atomicAdd(&sdeg[e & 255u], 1);
      lcol[pos] = (int)(e >> 8);
    }
  }
  __syncthreads();
  int T = cnt + nloc;
  for (int i = t; i < T; i += 256) col[gbase + i] = lcol[i];
}

// ---------------- GAT aggregation: 16 lanes/node, 4 nodes/wave ----------------
#define AGG_SLOT(K, QREG)                                                  \
  if (K == 0 || jj + K < trips) {                                          \
    float wj = __shfl(wgt, gb | (jj + K));                                 \
    uint4 cur = QREG;                                                      \
    if (jj + K + 4 < trips) {                                              \
      int sq = __shfl(s, gb | (jj + K + 4));                               \
      QREG = *(const uint4*)(h + (size_t)sq * 128 + li * 8);               \
    }                                                                      \
    float2 f0 = __half22float2(*(__half2*)&cur.x);                         \
    float2 f1 = __half22float2(*(__half2*)&cur.y);                         \
    float2 f2 = __half22float2(*(__half2*)&cur.z);                         \
    float2 f3 = __half22float2(*(__half2*)&cur.w);                         \
    acc0 = fmaf(f0.x, wj, acc0); acc1 = fmaf(f0.y, wj, acc1);              \
    acc2 = fmaf(f1.x, wj, acc2); acc3 = fmaf(f1.y, wj, acc3);              \
    acc4 = fmaf(f2.x, wj, acc4); acc5 = fmaf(f2.y, wj, acc5);              \
    acc6 = fmaf(f3.x, wj, acc6); acc7 = fmaf(f3.y, wj, acc7);              \
  }

template <bool HEADS>
__global__ __launch_bounds__(256) void k_agg_t(const __half* __restrict__ h,
                                               const float* __restrict__ as_,
                                               const float* __restrict__ ad_,
                                               const int* __restrict__ rowptr,
                                               const int* __restrict__ col,
                                               const float* __restrict__ bias,
                                               void* __restrict__ outp,
                                               const float* __restrict__ Wf,
                                               const float* __restrict__ bf,
                                               const float* __restrict__ Wsk,
                                               const float* __restrict__ bs,
                                               int n) {
  int gid = blockIdx.x * 256 + threadIdx.x;
  int wid = gid >> 6;
  int lane = gid & 63;
  int g = lane >> 4;
  int li = lane & 15;
  int gb = lane & 48;
  int node = wid * 4 + g;
  bool valid = node < n;
  int beg = 0, end = 0;
  float adv = 0.f;
  if (valid) {
    beg = rowptr[node];
    end = rowptr[node + 1];
    adv = ad_[node];
  }
  int deg = end - beg;
  int md = deg;
  md = max(md, __shfl_xor(md, 16));
  md = max(md, __shfl_xor(md, 32));

  float acc0 = 0.f, acc1 = 0.f, acc2 = 0.f, acc3 = 0.f;
  float acc4 = 0.f, acc5 = 0.f, acc6 = 0.f, acc7 = 0.f;
  float den_l = 0.f;

  for (int base = 0; base < md; base += 16) {
    int s = 0;
    float wgt = 0.f;
    if (base + li < deg) {
      s = col[beg + base + li];
      if ((unsigned)s >= (unsigned)n) s = 0;
      float v = as_[s] + adv;
      v = (v > 0.f) ? v : 0.2f * v;
      wgt = __expf(v);
    }
    den_l += wgt;

    int rem = md - base;
    int trips = rem > 16 ? 16 : rem;  // wave-uniform
    uint4 q0 = make_uint4(0u, 0u, 0u, 0u);
    uint4 q1 = q0, q2 = q0, q3 = q0;
    {
      int sq = __shfl(s, gb);
      q0 = *(const uint4*)(h + (size_t)sq * 128 + li * 8);
      if (trips > 1) { sq = __shfl(s, gb | 1); q1 = *(const uint4*)(h + (size_t)sq * 128 + li * 8); }
      if (trips > 2) { sq = __shfl(s, gb | 2); q2 = *(const uint4*)(h + (size_t)sq * 128 + li * 8); }
      if (trips > 3) { sq = __shfl(s, gb | 3); q3 = *(const uint4*)(h + (size_t)sq * 128 + li * 8); }
    }
    for (int jj = 0; jj < trips; jj += 4) {
      AGG_SLOT(0, q0)
      AGG_SLOT(1, q1)
      AGG_SLOT(2, q2)
      AGG_SLOT(3, q3)
    }
  }

  float den = sum16(den_l);
  float inv = 1.0f / den;

  float4 bv0 = *(const float4*)&bias[li * 8];
  float4 bv1 = *(const float4*)&bias[li * 8 + 4];
  float o0 = fmaxf(fmaf(acc0, inv, bv0.x), 0.f);
  float o1 = fmaxf(fmaf(acc1, inv, bv0.y), 0.f);
  float o2 = fmaxf(fmaf(acc2, inv, bv0.z), 0.f);
  float o3 = fmaxf(fmaf(acc3, inv, bv0.w), 0.f);
  float o4 = fmaxf(fmaf(acc4, inv, bv1.x), 0.f);
  float o5 = fmaxf(fmaf(acc5, inv, bv1.y), 0.f);
  float o6 = fmaxf(fmaf(acc6, inv, bv1.z), 0.f);
  float o7 = fmaxf(fmaf(acc7, inv, bv1.w), 0.f);

  if (!HEADS) {
    if (valid) {
      union { __half2 h2[4]; uint4 u; } pk;
      pk.h2[0] = __floats2half2_rn(o0, o1);
      pk.h2[1] = __floats2half2_rn(o2, o3);
      pk.h2[2] = __floats2half2_rn(o4, o5);
      pk.h2[3] = __floats2half2_rn(o6, o7);
      *(uint4*)&(((__half*)outp)[(size_t)node * 128 + li * 8]) = pk.u;
    }
  } else {
    float p[10];
#pragma unroll
    for (int j = 0; j < 3; ++j) {
      float4 w0 = *(const float4*)&Wf[(size_t)j * 128 + li * 8];
      float4 w1 = *(const float4*)&Wf[(size_t)j * 128 + li * 8 + 4];
      p[j] = o0 * w0.x + o1 * w0.y + o2 * w0.z + o3 * w0.w +
             o4 * w1.x + o5 * w1.y + o6 * w1.z + o7 * w1.w;
    }
#pragma unroll
    for (int j = 0; j < 7; ++j) {
      float4 w0 = *(const float4*)&Wsk[(size_t)j * 128 + li * 8];
      float4 w1 = *(const float4*)&Wsk[(size_t)j * 128 + li * 8 + 4];
      p[3 + j] = o0 * w0.x + o1 * w0.y + o2 * w0.z + o3 * w0.w +
                 o4 * w1.x + o5 * w1.y + o6 * w1.z + o7 * w1.w;
    }
#pragma unroll
    for (int j = 0; j < 10; ++j) p[j] = sum16(p[j]);
    if (li == 0 && valid) {
      float* out = (float*)outp;
#pragma unroll
      for (int j = 0; j < 3; ++j) out[(size_t)node * 3 + j] = p[j] + bf[j];
      float* sk = out + (size_t)n * 3;
#pragma unroll
      for (int j = 0; j < 7; ++j) sk[(size_t)node * 7 + j] = p[3 + j] + bs[j];
    }
  }
}

// ---------------- launch ----------------
extern "C" void kernel_launch(void* const* d_in, const int* in_sizes, int n_in,
                              void* d_out, int out_size, void* d_ws, size_t ws_size,
                              hipStream_t stream) {
  const float* x = (const float*)d_in[0];
  const int* ei = (const int*)d_in[1];  // [2, E] int32
  const float* W1 = (const float*)d_in[2];
  const float* a_src1 = (const float*)d_in[3];
  const float* a_dst1 = (const float*)d_in[4];
  const float* b1 = (const float*)d_in[5];
  const float* W2 = (const float*)d_in[6];
  const float* a_src2 = (const float*)d_in[7];
  const float* a_dst2 = (const float*)d_in[8];
  const float* b2 = (const float*)d_in[9];
  const float* Wf = (const float*)d_in[10];
  const float* bf = (const float*)d_in[11];
  const float* Wsk = (const float*)d_in[12];
  const float* bs = (const float*)d_in[13];
  float* out = (float*)d_out;

  const int N = in_sizes[0] / 128;
  const int nE = in_sizes[1] / 2;
  const int NB = (N + BPB - 1) / BPB;   // buckets, <=512
  const int PB = (nE + EPB - 1) / EPB;  // partition blocks, <=256 for nE<=2M

  char* w = (char*)d_ws;
  auto carve = [&](size_t bytes) {
    char* p = w;
    w += (bytes + 255) & ~(size_t)255;
    return (void*)p;
  };
  __half* H16 = (__half*)carve((size_t)N * 128 * 2);  // GEMM out (row-major fp16)
  __half* B16 = (__half*)carve((size_t)N * 128 * 2);  // layer-1 agg out
  float* as_ = (float*)carve((size_t)N * 4);
  float* ad_ = (float*)carve((size_t)N * 4);
  int* rowptr = (int*)carve((size_t)(N + 1) * 4);
  int* col = (int*)carve((size_t)(nE + N) * 4);
  int* blkoff = (int*)carve((size_t)PB * (NB + 1) * 4);  // per-block local excl offsets
  unsigned* part = (unsigned*)carve((size_t)nE * 4);     // packed (src<<8)|dloc

  dim3 b256(256);
  const int gemm_blocks = (N + 63) / 64;
  const int agg_blocks = (((N + 3) / 4) * 64 + 255) / 256;  // 4 nodes/wave

  // ---- partition (block-local, coalesced) fused with layer-1 GEMM ----
  k_fused1<<<PB + gemm_blocks, b256, 0, stream>>>(ei, blkoff, part, nE, N, PB, NB,
                                                  x, W1, a_src1, a_dst1, H16, as_, ad_);
  k_bucket<<<NB, b256, 0, stream>>>(part, blkoff, rowptr, col, PB, NB, N);

  // ---- layer 1 aggregation ----
  k_agg_t<false><<<agg_blocks, b256, 0, stream>>>(H16, as_, ad_, rowptr, col, b1, B16,
                                                  nullptr, nullptr, nullptr, nullptr, N);

  // ---- layer 2 + fused heads ----
  k_linear2<<<gemm_blocks, b256, 0, stream>>>(B16, W2, a_src2, a_dst2, H16, as_, ad_, N);
  k_agg_t<true><<<agg_blocks, b256, 0, stream>>>(H16, as_, ad_, rowptr, col, b2, out,
                                                 Wf, bf, Wsk, bs, N);
}